// Round 5
// baseline (2017.299 us; speedup 1.0000x reference)
//
#include <hip/hip_runtime.h>
#include <stdint.h>

typedef int int32x4  __attribute__((ext_vector_type(4)));
typedef int int32x16 __attribute__((ext_vector_type(16)));

#define IN_F   4096
#define OUT_F  4096
#define ROWS   8192   /* 4 * 2048 */

#define BM 256
#define BN 256
#define BK 64
#define NT (IN_F / BK)           /* 64 K-tiles */
#define TILE_LDS 32768           /* A 16KB + B 16KB per tile */
#define LDS_TOTAL (2 * TILE_LDS) /* double buffer = 64 KB -> 2 blocks/CU */

// async global->LDS, 16B per lane; LDS dest must be lane-contiguous (m104/m108)
#define GLOAD_LDS16(g, l)                                                      \
  __builtin_amdgcn_global_load_lds(                                            \
      (const __attribute__((address_space(1))) void*)(g),                      \
      (__attribute__((address_space(3))) void*)(l), 16, 0, 0)

__device__ __forceinline__ int pack4i(int a, int b, int c, int d) {
  return (a & 0xff) | ((b & 0xff) << 8) | ((c & 0xff) << 16) | (d << 24);
}

// ---- fused conversion: x int32->int8 and w fp32->int8, grid-stride ---------
#define CVT_BLOCKS 2048
#define CVT_NX 8388608   /* 8192*4096/4 int4 chunks */
#define CVT_NT 12582912  /* + 4096*4096/4 float4 chunks */
__global__ void __launch_bounds__(256) cvt_kernel(const int4* __restrict__ x,
                                                  const float4* __restrict__ w,
                                                  int* __restrict__ ox,
                                                  int* __restrict__ ow) {
  size_t i = (size_t)blockIdx.x * 256 + threadIdx.x;
  for (; i < CVT_NT; i += (size_t)CVT_BLOCKS * 256) {
    if (i < CVT_NX) {            // wave-uniform: CVT_NX % 256 == 0
      int4 a = x[i];
      ox[i] = pack4i(a.x, a.y, a.z, a.w);
    } else {
      size_t j = i - CVT_NX;
      float4 a = w[j];
      ow[j] = pack4i(__float2int_rn(a.x), __float2int_rn(a.y),
                     __float2int_rn(a.z), __float2int_rn(a.w));
    }
  }
}

// ---- i8 MFMA GEMM: C[m,n] = sum_k A[m,k]*B[n,k] (row-major [rows][K]) ------
// 256x256 block, BK=64, 8 waves (2x4), per-wave 128x64 via 4x2 of
// mfma_i32_32x32x32_i8.
//
// Cycle model from r0-r4 (validated: r1's 2963 cyc/tile = 1170 MFMA + 1536
// conflict-taxed reads, serial): the limiter is lockstep phase serialization
// at 1 block/CU plus, in r3/r4, uncoalesced DMA source (64 lines/instr).
//
// 16-ROW-BLOCKED K-OUTER LDS LAYOUT — solves BOTH sides of the duality:
//   phys 16B-unit = (r>>4)*64 + c*16 + (r&15)     (c = k-chunk 0..3)
//   * fragment read (fixed c, 32 consecutive rows): two contiguous 512B
//     spans -> m134 stride-1 regime, 0 bank conflicts.
//   * forced DMA thread<->global map: thread t -> row (t>>6)*16+(t&15),
//     chunk (t>>4)&3 -> a wave reads 16 rows x full 64B lines = 4 lanes/line,
//     fully coalesced (r1-grade), vs full-K-outer's 64 lines/instr (the
//     r3/r4 regression).
//
// 2 BLOCKS/CU (the overlap fix): 64KB LDS/block double-buffer -> two
// independent 8-wave blocks per CU; block A's read phase overlaps block B's
// MFMA phase (m114 mechanism).  ONE barrier/tile, depth-1 prefetch; the
// vmcnt(0) gate is non-blocking in steady state (loads issued a full tile
// body earlier).  Buffer safety: issue(t+1) writes buf[(t+1)&1], whose
// readers (tile t-1) finished their lgkm-waited ds_reads before reaching
// the gate barrier of tile t.
//
// Fragment lane maps (harness-verified): A/B: m|n = lane&31, k-bytes =
// (lane>>5)*16 within the 32B k-slice.  C/D: col = lane&31,
// row = (reg&3) + 8*(reg>>2) + 4*(lane>>5).
__global__ void __launch_bounds__(512, 4) gemm_i8_kernel(
    const int8_t* __restrict__ A8, const int8_t* __restrict__ B8,
    const float* __restrict__ bias, const float* __restrict__ alpha_p,
    int* __restrict__ out) {
  extern __shared__ int8_t lds[];

  const int t    = threadIdx.x;
  const int wave = t >> 6;
  const int lane = t & 63;
  const int l31  = lane & 31;
  const int hi   = lane >> 5;   // 0..1
  const int wm   = wave >> 2;   // 0..1  (M rows of waves)
  const int wn   = wave & 3;    // 0..3  (N cols of waves)

  // XCD-aware bijective swizzle (T1): 512 blocks % 8 == 0.
  const int flat = blockIdx.y * gridDim.x + blockIdx.x;  // 0..511
  const int wid  = (flat & 7) * 64 + (flat >> 3);
  const int bm   = wid >> 4;    // 0..31
  const int bn   = wid & 15;    // 0..15

  // staging source (16-row-blocked K-outer map):
  // thread t -> row (t>>6)*16 + (t&15), chunk (t>>4)&3; round j adds 128 rows.
  const int rS = ((t >> 6) << 4) + (t & 15);
  const int cS = ((t >> 4) & 3) * 16;
  const int8_t* gA = A8 + (size_t)(bm * BM + rS) * IN_F + cS;
  const int8_t* gB = B8 + (size_t)(bn * BN + rS) * IN_F + cS;
  const int ldst = t * 16;

  // fragment read index (16B units): (row>>4)*64 + c*16 + (row&15)
  // row = base + l31 (base mult of 32) -> base*4 + (l31>>4)*64 + (l31&15) + c*16
  const int ridx  = ((l31 >> 4) << 6) + (l31 & 15);
  const int aBase = wm * 512 + ridx;   // (wm*128)*4 + ridx ; +mi*128 per mi
  const int bBase = wn * 256 + ridx;   // (wn*64)*4  + ridx ; +ni*128 per ni

  int32x16 acc[4][2] = {};

  auto issue = [&](int tile) {
    int8_t* base = lds + (tile & 1) * TILE_LDS;
    const int k0 = tile * BK;
    GLOAD_LDS16(gA + k0,                      base + ldst);           // A r0-127
    GLOAD_LDS16(gA + k0 + (size_t)128 * IN_F, base + 8192 + ldst);    // A r128-255
    GLOAD_LDS16(gB + k0,                      base + 16384 + ldst);
    GLOAD_LDS16(gB + k0 + (size_t)128 * IN_F, base + 24576 + ldst);
  };

  issue(0);

  for (int tt = 0; tt < NT; ++tt) {
    // gate: own tile-tt DMA done (non-blocking in steady state) + all waves
    asm volatile("s_waitcnt vmcnt(0)" ::: "memory");
    __builtin_amdgcn_s_barrier();
    if (tt + 1 < NT) issue(tt + 1);     // prefetch into the other buffer

    const int32x4* As4 = (const int32x4*)(lds + (tt & 1) * TILE_LDS);
    const int32x4* Bs4 = As4 + 1024;    // +16 KB
#pragma unroll
    for (int ks = 0; ks < 2; ++ks) {
      const int ksw16 = (ks * 2 + hi) * 16;   // k-chunk plane * 16 units
      int32x4 af[4], bf[2];
#pragma unroll
      for (int mi = 0; mi < 4; ++mi) af[mi] = As4[aBase + mi * 128 + ksw16];
#pragma unroll
      for (int ni = 0; ni < 2; ++ni) bf[ni] = Bs4[bBase + ni * 128 + ksw16];
      __builtin_amdgcn_s_setprio(1);    // T5: favor MFMA-phase waves
#pragma unroll
      for (int mi = 0; mi < 4; ++mi)
#pragma unroll
        for (int ni = 0; ni < 2; ++ni)
          acc[mi][ni] = __builtin_amdgcn_mfma_i32_32x32x32_i8(
              af[mi], bf[ni], acc[mi][ni], 0, 0, 0);
      __builtin_amdgcn_s_setprio(0);
    }
  }

  // epilogue: C/D col = lane&31, row = (reg&3) + 8*(reg>>2) + 4*hi
  const float alpha = *alpha_p;
#pragma unroll
  for (int mi = 0; mi < 4; ++mi) {
    const int rowt = bm * BM + wm * 128 + mi * 32 + hi * 4;
#pragma unroll
    for (int ni = 0; ni < 2; ++ni) {
      const int col = bn * BN + wn * 64 + ni * 32 + l31;
      const float bv = bias[col];
#pragma unroll
      for (int r = 0; r < 16; ++r) {
        const int row = rowt + (r & 3) + 8 * (r >> 2);
        float v = rintf((float)acc[mi][ni][r] * alpha + bv);
        v = fminf(fmaxf(v, -128.f), 127.f);
        out[(size_t)row * OUT_F + col] = (int)v;
      }
    }
  }
}

extern "C" void kernel_launch(void* const* d_in, const int* in_sizes, int n_in,
                              void* d_out, int out_size, void* d_ws, size_t ws_size,
                              hipStream_t stream) {
  const int*   x     = (const int*)d_in[0];    // [8192, 4096] int8-valued
  const float* w     = (const float*)d_in[1];  // [4096, 4096] int8-valued
  const float* bias  = (const float*)d_in[2];  // [4096]
  const float* alpha = (const float*)d_in[3];  // scalar
  int* out = (int*)d_out;                      // [8192, 4096] int32 (int8 values)

  int8_t* x8 = (int8_t*)d_ws;                        // 33,554,432 B
  int8_t* w8 = x8 + (size_t)ROWS * IN_F;             // 16,777,216 B (total 48 MB)

  static bool attr_done = false;
  if (!attr_done) {
    (void)hipFuncSetAttribute(reinterpret_cast<const void*>(gemm_i8_kernel),
                              hipFuncAttributeMaxDynamicSharedMemorySize,
                              LDS_TOTAL);
    attr_done = true;
  }

  cvt_kernel<<<CVT_BLOCKS, 256, 0, stream>>>((const int4*)x, (const float4*)w,
                                             (int*)x8, (int*)w8);

  dim3 grid(OUT_F / BN, ROWS / BM);  // (16, 32) = 512 blocks, 2 clean rounds
  gemm_i8_kernel<<<grid, 512, LDS_TOTAL, stream>>>(x8, w8, bias, alpha, out);
}

// Round 7
// 411.930 us; speedup vs baseline: 4.8972x; 4.8972x over previous
//
#include <hip/hip_runtime.h>
#include <stdint.h>

typedef int int32x4  __attribute__((ext_vector_type(4)));
typedef int int32x16 __attribute__((ext_vector_type(16)));

#define IN_F   4096
#define OUT_F  4096
#define ROWS   8192   /* 4 * 2048 */

#define BM 256
#define BN 256
#define BK 64
#define NT (IN_F / BK)           /* 64 K-tiles */
#define TILE_LDS 32768           /* A 16KB + B 16KB per tile */
#define LDS_TOTAL (4 * TILE_LDS) /* quad buffer = 128 KB (dynamic) */

// async global->LDS, 16B per lane; LDS dest must be lane-contiguous (m104/m108)
#define GLOAD_LDS16(g, l)                                                      \
  __builtin_amdgcn_global_load_lds(                                            \
      (const __attribute__((address_space(1))) void*)(g),                      \
      (__attribute__((address_space(3))) void*)(l), 16, 0, 0)

__device__ __forceinline__ int pack4i(int a, int b, int c, int d) {
  return (a & 0xff) | ((b & 0xff) << 8) | ((c & 0xff) << 16) | (d << 24);
}

// ---- fused conversion: x int32->int8 and w fp32->int8, grid-stride ---------
#define CVT_BLOCKS 2048
#define CVT_NX 8388608   /* 8192*4096/4 int4 chunks */
#define CVT_NT 12582912  /* + 4096*4096/4 float4 chunks */
__global__ void __launch_bounds__(256) cvt_kernel(const int4* __restrict__ x,
                                                  const float4* __restrict__ w,
                                                  int* __restrict__ ox,
                                                  int* __restrict__ ow) {
  size_t i = (size_t)blockIdx.x * 256 + threadIdx.x;
  for (; i < CVT_NT; i += (size_t)CVT_BLOCKS * 256) {
    if (i < CVT_NX) {            // wave-uniform: CVT_NX % 256 == 0
      int4 a = x[i];
      ox[i] = pack4i(a.x, a.y, a.z, a.w);
    } else {
      size_t j = i - CVT_NX;
      float4 a = w[j];
      ow[j] = pack4i(__float2int_rn(a.x), __float2int_rn(a.y),
                     __float2int_rn(a.z), __float2int_rn(a.w));
    }
  }
}

// ---- i8 MFMA GEMM: C[m,n] = sum_k A[m,k]*B[n,k] (row-major [rows][K]) ------
// 256x256 block, BK=64, 8 waves (2x4), per-wave 128x64 via 4x2 of
// mfma_i32_32x32x32_i8.  1 block/CU (acc = 128 regs/wave makes >2 waves/SIMD
// impossible — r5's forced launch_bounds(512,4) spilled acc: 9.3 GB scratch
// traffic, MfmaUtil 3%.  NEVER cap regs below the accumulator footprint).
//
// Cycle model (r1 validated): per CU per K-tile, MFMA pipe ~1170 cyc and LDS
// port ~1152 cyc (96 x ds_read_b128 @ 12 cyc, shared per CU) — a dead heat.
// r1's {all reads -> barrier -> lgkm(0) -> all MFMAs} serialized them (2963
// cyc/tile).  Fix: software-pipeline at ks granularity — issue the NEXT
// phase's 6 ds_reads (cheap wave-issue) BEFORE the current 8-MFMA cluster, so
// the port drains under the pipe.  Compiler places counted lgkm waits (its
// verified strength, m97 asm); no sched_barrier pins (m141 lesson).
//
// 16-ROW-BLOCKED K-OUTER LDS LAYOUT (r5-verified: conflicts = 0, coalesced
// DMA source): phys 16B-unit = (r>>4)*64 + c*16 + (r&15), c = k-chunk 0..3.
// Fragment reads = contiguous 256B spans per 16 lanes; DMA source = 16 rows
// x full 64B lines (4 lanes/line).
//
// DMA pipeline: quad buffer, depth 3.  Gate = counted vmcnt(4) (waits tile
// t+1; t+2 stays in flight) + s_barrier; vmcnt(0) for the last 2 tiles
// (outstanding <= 4 there, vmcnt(4) would no-op unsafely).  issue(t+3) after
// the gate overwrites buf[(t-1)&3], whose last readers (ks1(t-1) fragments)
// were consumed before body(t-1)'s MFMAs, one barrier earlier.  Safe.
//
// Fragment lane maps (harness-verified): A/B: m|n = lane&31, k-bytes =
// (lane>>5)*16 within the 32B k-slice.  C/D: col = lane&31,
// row = (reg&3) + 8*(reg>>2) + 4*(lane>>5).
__global__ void __launch_bounds__(512) gemm_i8_kernel(
    const int8_t* __restrict__ A8, const int8_t* __restrict__ B8,
    const float* __restrict__ bias, const float* __restrict__ alpha_p,
    int* __restrict__ out) {
  extern __shared__ int8_t lds[];

  const int t    = threadIdx.x;
  const int wave = t >> 6;
  const int lane = t & 63;
  const int l31  = lane & 31;
  const int hi   = lane >> 5;   // 0..1
  const int wm   = wave >> 2;   // 0..1  (M rows of waves)
  const int wn   = wave & 3;    // 0..3  (N cols of waves)

  // XCD-aware bijective swizzle (T1): 512 blocks % 8 == 0.
  const int flat = blockIdx.y * gridDim.x + blockIdx.x;  // 0..511
  const int wid  = (flat & 7) * 64 + (flat >> 3);
  const int bm   = wid >> 4;    // 0..31
  const int bn   = wid & 15;    // 0..15

  // staging source (16-row-blocked K-outer map):
  // thread t -> row (t>>6)*16 + (t&15), chunk (t>>4)&3; round j adds 128 rows.
  const int rS = ((t >> 6) << 4) + (t & 15);
  const int cS = ((t >> 4) & 3) * 16;
  const int8_t* gA = A8 + (size_t)(bm * BM + rS) * IN_F + cS;
  const int8_t* gB = B8 + (size_t)(bn * BN + rS) * IN_F + cS;
  const int ldst = t * 16;

  // fragment read index (16B units): (row>>4)*64 + c*16 + (row&15)
  const int ridx  = ((l31 >> 4) << 6) + (l31 & 15);
  const int aBase = wm * 512 + ridx;   // +mi*128 per mi
  const int bBase = wn * 256 + ridx;   // +ni*128 per ni

  int32x16 acc[4][2] = {};
  int32x4 afA[4], bfA[2];   // ks0 fragments
  int32x4 afB[4], bfB[2];   // ks1 fragments

  auto issue = [&](int tile) {
    int8_t* base = lds + (tile & 3) * TILE_LDS;
    const int k0 = tile * BK;
    GLOAD_LDS16(gA + k0,                      base + ldst);           // A r0-127
    GLOAD_LDS16(gA + k0 + (size_t)128 * IN_F, base + 8192 + ldst);    // A r128-255
    GLOAD_LDS16(gB + k0,                      base + 16384 + ldst);
    GLOAD_LDS16(gB + k0 + (size_t)128 * IN_F, base + 24576 + ldst);
  };

  auto readf = [&](int tile, int ks, int32x4* af, int32x4* bf) {
    const int32x4* As4 = (const int32x4*)(lds + (tile & 3) * TILE_LDS);
    const int32x4* Bs4 = As4 + 1024;    // +16 KB
    const int ksw16 = (ks * 2 + hi) * 16;
#pragma unroll
    for (int mi = 0; mi < 4; ++mi) af[mi] = As4[aBase + mi * 128 + ksw16];
#pragma unroll
    for (int ni = 0; ni < 2; ++ni) bf[ni] = Bs4[bBase + ni * 128 + ksw16];
  };

  auto mfma8 = [&](int32x4* af, int32x4* bf) {
    __builtin_amdgcn_s_setprio(1);      // T5: MFMA cluster priority
#pragma unroll
    for (int mi = 0; mi < 4; ++mi)
#pragma unroll
      for (int ni = 0; ni < 2; ++ni)
        acc[mi][ni] = __builtin_amdgcn_mfma_i32_32x32x32_i8(
            af[mi], bf[ni], acc[mi][ni], 0, 0, 0);
    __builtin_amdgcn_s_setprio(0);
  };

  // prologue: tiles 0..2 in flight; wait tile 0 (leave 1,2 flying)
  issue(0); issue(1); issue(2);
  asm volatile("s_waitcnt vmcnt(8)" ::: "memory");
  __builtin_amdgcn_s_barrier();
  readf(0, 0, afA, bfA);

  for (int tt = 0; tt < NT; ++tt) {
    readf(tt, 1, afB, bfB);             // ks1 reads -> port drains under...
    mfma8(afA, bfA);                    // ...MFMA ks0(tt)
    // gate: tile tt+1 landed (tt+2 stays in flight), all waves past their
    // reads of buf[tt-1] (consumed one barrier ago)
    if (tt < NT - 2) {
      asm volatile("s_waitcnt vmcnt(4)" ::: "memory");
    } else {
      asm volatile("s_waitcnt vmcnt(0)" ::: "memory");
    }
    __builtin_amdgcn_s_barrier();
    if (tt + 3 < NT) issue(tt + 3);
    if (tt + 1 < NT) readf(tt + 1, 0, afA, bfA);  // ks0(tt+1) under MFMA ks1
    mfma8(afB, bfB);                    // MFMA ks1(tt)
  }

  // epilogue: C/D col = lane&31, row = (reg&3) + 8*(reg>>2) + 4*hi
  const float alpha = *alpha_p;
#pragma unroll
  for (int mi = 0; mi < 4; ++mi) {
    const int rowt = bm * BM + wm * 128 + mi * 32 + hi * 4;
#pragma unroll
    for (int ni = 0; ni < 2; ++ni) {
      const int col = bn * BN + wn * 64 + ni * 32 + l31;
      const float bv = bias[col];
#pragma unroll
      for (int r = 0; r < 16; ++r) {
        const int row = rowt + (r & 3) + 8 * (r >> 2);
        float v = rintf((float)acc[mi][ni][r] * alpha + bv);
        v = fminf(fmaxf(v, -128.f), 127.f);
        out[(size_t)row * OUT_F + col] = (int)v;
      }
    }
  }
}

extern "C" void kernel_launch(void* const* d_in, const int* in_sizes, int n_in,
                              void* d_out, int out_size, void* d_ws, size_t ws_size,
                              hipStream_t stream) {
  const int*   x     = (const int*)d_in[0];    // [8192, 4096] int8-valued
  const float* w     = (const float*)d_in[1];  // [4096, 4096] int8-valued
  const float* bias  = (const float*)d_in[2];  // [4096]
  const float* alpha = (const float*)d_in[3];  // scalar
  int* out = (int*)d_out;                      // [8192, 4096] int32 (int8 values)

  int8_t* x8 = (int8_t*)d_ws;                        // 33,554,432 B
  int8_t* w8 = x8 + (size_t)ROWS * IN_F;             // 16,777,216 B (total 48 MB)

  static bool attr_done = false;
  if (!attr_done) {
    (void)hipFuncSetAttribute(reinterpret_cast<const void*>(gemm_i8_kernel),
                              hipFuncAttributeMaxDynamicSharedMemorySize,
                              LDS_TOTAL);
    attr_done = true;
  }

  cvt_kernel<<<CVT_BLOCKS, 256, 0, stream>>>((const int4*)x, (const float4*)w,
                                             (int*)x8, (int*)w8);

  dim3 grid(OUT_F / BN, ROWS / BM);  // (16, 32) = 512 blocks, 2 clean rounds
  gemm_i8_kernel<<<grid, 512, LDS_TOTAL, stream>>>(x8, w8, bias, alpha, out);
}